// Round 11
// baseline (299.298 us; speedup 1.0000x reference)
//
#include <hip/hip_runtime.h>
#include <hip/hip_bf16.h>

// ---------------- problem constants ----------------
#define B_TOTAL   32768
#define L_SITES   256
#define N_MID     254        // L-2 middle sites
#define HALF_PI_F 1.57079632679489662f
#define EPS_NORM  1e-8f

// ---------------- ws layout (float/dword slots) ----------------
// [WS_FRAG .. +520191]  B-fragment table: 254 steps x 8 frags x 64 lanes x 4 dwords
//                       frag q = h*4 + kh*2 + p  (h: n-half, kh: feature, p: 0=hi,1=lo)
// [WS_C0   .. +63]      core0 fp32  [f][32]
// [WS_CN   .. +639]     coreN fp32  [f][a][10]
// [WS_X    .. +8388607] xT fp32 [L][B]  (transposed)
// [WS_FLAG]             u32 flag: 1 = inputs are bf16, 0 = fp32
#define WS_FRAG 0
#define WS_C0   520192
#define WS_CN   520256
#define WS_X    520896
#define WS_FLAG 8909504

typedef short bf16x8 __attribute__((ext_vector_type(8)));
typedef float f32x4  __attribute__((ext_vector_type(4)));

__device__ __forceinline__ unsigned short f2bf(float f) {
    unsigned u = __builtin_bit_cast(unsigned, f);
    u += 0x7FFFu + ((u >> 16) & 1u);          // RNE
    return (unsigned short)(u >> 16);
}
__device__ __forceinline__ float bf2f(unsigned short h) {
    unsigned u = ((unsigned)h) << 16;
    return __builtin_bit_cast(float, u);
}
__device__ __forceinline__ bf16x8 asbf(uint4 u) {
    return __builtin_bit_cast(bf16x8, u);
}
// packed RNE f32x2 -> bf16x2 (v_cvt_pk_bf16_f32); bit-identical to scalar f2bf
// for normal values (both RNE) — proven passing in round 8
__device__ __forceinline__ unsigned pkbf2(float a, float b) {
    float2 p; p.x = a; p.y = b;
    __hip_bfloat162 h2 = __float22bfloat162_rn(p);
    unsigned u;
    __builtin_memcpy(&u, &h2, 4);
    return u;                                  // a in bits 0..15, b in 16..31
}
// split 8 fp32 into hi/lo bf16 fragments via packed cvt (round-8 proven)
__device__ __forceinline__ void split8(const float* v, bf16x8& hi, bf16x8& lo) {
    uint4 H, L;
    unsigned* hp = (unsigned*)&H;
    unsigned* lp = (unsigned*)&L;
    #pragma unroll
    for (int d = 0; d < 4; ++d) {
        float a = v[2 * d], b = v[2 * d + 1];
        unsigned hb = pkbf2(a, b);
        float h0 = __builtin_bit_cast(float, hb << 16);
        float h1 = __builtin_bit_cast(float, hb & 0xFFFF0000u);
        hp[d] = hb;
        lp[d] = pkbf2(a - h0, b - h1);         // exact residuals
    }
    hi = __builtin_bit_cast(bf16x8, H);
    lo = __builtin_bit_cast(bf16x8, L);
}
// per-wave input-dtype flag: bf16 pairs always have low16 < 0x4000
__device__ __forceinline__ bool detect_bf16(const unsigned* x_raw, int lane) {
    unsigned v = x_raw[lane];
    return __ballot((v & 0xFFFFu) >= 0x4000u) == 0ull;
}

// ---------------- fused aux kernel (round-8 proven, unchanged) ----------------
__global__ __launch_bounds__(256)
void aux_all(const void* __restrict__ x_in, const void* __restrict__ c0_in,
             const void* __restrict__ am_in, const void* __restrict__ cn_in,
             float* __restrict__ ws) {
    const int lane = threadIdx.x & 63;
    const bool bf = detect_bf16((const unsigned*)x_in, lane);
    const int b = blockIdx.x;

    if (b < 2048) {
        __shared__ float tile[64][65];
        const int bb = (b & 511) * 64;
        const int ll = (b >> 9) * 64;
        #pragma unroll
        for (int k = 0; k < 16; ++k) {
            int idx = threadIdx.x + k * 256;
            int row = idx >> 6, col = idx & 63;
            size_t gi = (size_t)(bb + row) * L_SITES + ll + col;
            float v = bf ? bf2f(((const unsigned short*)x_in)[gi])
                         : ((const float*)x_in)[gi];
            tile[row][col] = v;
        }
        __syncthreads();
        #pragma unroll
        for (int k = 0; k < 16; ++k) {
            int idx = threadIdx.x + k * 256;
            int row = idx >> 6, col = idx & 63;
            ws[WS_X + (size_t)(ll + row) * B_TOTAL + bb + col] = tile[col][row];
        }
    } else if (b < 2556) {
        int i = (b - 2048) * 256 + threadIdx.x;
        if (i < N_MID * 8 * 64) {
            const int l  = i & 63;
            const int q  = (i >> 6) & 7;
            const int t  = i >> 9;
            const int h  = q >> 2;
            const int kh = (q >> 1) & 1;
            const int p  = q & 1;
            const int n  = h * 16 + (l & 15);
            const int kb = (l >> 4) * 8;
            unsigned dw[4];
            #pragma unroll
            for (int d = 0; d < 4; ++d) {
                unsigned e01[2];
                #pragma unroll
                for (int s = 0; s < 2; ++s) {
                    int a = kb + 2 * d + s;
                    size_t idx = ((size_t)(t * 2 + kh) * 32 + a) * 32 + n;
                    float v = bf ? bf2f(((const unsigned short*)am_in)[idx])
                                 : ((const float*)am_in)[idx];
                    unsigned short hi = f2bf(v);
                    e01[s] = (p == 0) ? hi : f2bf(v - bf2f(hi));
                }
                dw[d] = e01[0] | (e01[1] << 16);
            }
            uint4 o; o.x = dw[0]; o.y = dw[1]; o.z = dw[2]; o.w = dw[3];
            ((uint4*)ws)[(size_t)(t * 8 + q) * 64 + l] = o;
        }
    } else {
        for (int i = threadIdx.x; i < 640; i += 256) {
            if (i < 64)
                ws[WS_C0 + i] = bf ? bf2f(((const unsigned short*)c0_in)[i])
                                   : ((const float*)c0_in)[i];
            ws[WS_CN + i] = bf ? bf2f(((const unsigned short*)cn_in)[i])
                               : ((const float*)cn_in)[i];
        }
        if (threadIdx.x == 0)
            *(unsigned*)(ws + WS_FLAG) = bf ? 1u : 0u;
    }
}

// ---------------- main chain kernel ----------------
// Bit-policy kernel: the chain computes EXACTLY round-7's bits (proven absmax
// 4.88e-3): two scaled splits [ct*M ; st*M] (no fold-after), 4x 3-MFMA chains +
// pairwise adds, stride-33 LDS transpose, PER-STEP normalization, ocml sincos.
// Only bit-neutral changes on top: packed split (RNE==scalar RNE), register
// prefetch of next-step frags/x (same loads issued one iteration early).
__global__ __launch_bounds__(256)
void mps_mfma(const float* __restrict__ ws, void* __restrict__ out) {
    __shared__ float T[4][528];                 // per-wave 16 rows x stride 33
    const int lane = threadIdx.x & 63;
    const int w    = threadIdx.x >> 6;
    const int r    = lane & 15;
    const int quad = lane >> 4;
    const int b0   = (blockIdx.x * 4 + w) * 16;
    const float* __restrict__ xT = ws + WS_X;
    const uint4* __restrict__ BF = (const uint4*)ws;   // WS_FRAG = 0
    float* __restrict__ Tw = &T[w][0];

    // ---- M0 in row-major k-slice order (not normalized, per reference) ----
    float mm[8];
    {
        float x0 = xT[b0 + r];
        float sn, cs; __sincosf(HALF_PI_F * x0, &sn, &cs);
        const float* c0 = ws + WS_C0;
        #pragma unroll
        for (int j = 0; j < 8; ++j) {
            int a = quad * 8 + j;
            mm[j] = cs * c0[a] + sn * c0[32 + a];
        }
    }

    // frag + x software pipeline (pure scheduling; values identical)
    uint4 cur[8];
    {
        const uint4* Bt = BF + lane;
        #pragma unroll
        for (int q = 0; q < 8; ++q) cur[q] = Bt[q * 64];
    }
    float xc = xT[(size_t)B_TOTAL + b0 + r];   // x for site 1 (t=0)

    #pragma unroll 1
    for (int t = 0; t < N_MID; ++t) {
        // prefetch next step's fragments and x (t=253 reloads same frags; x = site 255)
        const int tn = (t + 1 < N_MID) ? (t + 1) : t;
        const uint4* Bn = BF + (size_t)(tn * 8) * 64 + lane;
        uint4 nxt[8];
        #pragma unroll
        for (int q = 0; q < 8; ++q) nxt[q] = Bn[q * 64];
        float xn = xT[(size_t)(2 + t) * B_TOTAL + b0 + r];

        float st, ct; __sincosf(HALF_PI_F * xc, &st, &ct);

        // scaled stacked A-operand rows: [ct*M ; st*M]  (two splits — proven)
        float s0[8], s1[8];
        #pragma unroll
        for (int j = 0; j < 8; ++j) { s0[j] = ct * mm[j]; s1[j] = st * mm[j]; }
        bf16x8 m0h, m0l, m1h, m1l;
        split8(s0, m0h, m0l);
        split8(s1, m1h, m1l);

        const f32x4 z = {0.f, 0.f, 0.f, 0.f};
        // 4 independent 3-chains (h x kh), then add kh-halves (round-7 order)
        f32x4 a00 = __builtin_amdgcn_mfma_f32_16x16x32_bf16(m0h, asbf(cur[0]), z, 0, 0, 0);
        a00 = __builtin_amdgcn_mfma_f32_16x16x32_bf16(m0l, asbf(cur[0]), a00, 0, 0, 0);
        a00 = __builtin_amdgcn_mfma_f32_16x16x32_bf16(m0h, asbf(cur[1]), a00, 0, 0, 0);
        f32x4 a01 = __builtin_amdgcn_mfma_f32_16x16x32_bf16(m1h, asbf(cur[2]), z, 0, 0, 0);
        a01 = __builtin_amdgcn_mfma_f32_16x16x32_bf16(m1l, asbf(cur[2]), a01, 0, 0, 0);
        a01 = __builtin_amdgcn_mfma_f32_16x16x32_bf16(m1h, asbf(cur[3]), a01, 0, 0, 0);
        f32x4 a10 = __builtin_amdgcn_mfma_f32_16x16x32_bf16(m0h, asbf(cur[4]), z, 0, 0, 0);
        a10 = __builtin_amdgcn_mfma_f32_16x16x32_bf16(m0l, asbf(cur[4]), a10, 0, 0, 0);
        a10 = __builtin_amdgcn_mfma_f32_16x16x32_bf16(m0h, asbf(cur[5]), a10, 0, 0, 0);
        f32x4 a11 = __builtin_amdgcn_mfma_f32_16x16x32_bf16(m1h, asbf(cur[6]), z, 0, 0, 0);
        a11 = __builtin_amdgcn_mfma_f32_16x16x32_bf16(m1l, asbf(cur[6]), a11, 0, 0, 0);
        a11 = __builtin_amdgcn_mfma_f32_16x16x32_bf16(m1h, asbf(cur[7]), a11, 0, 0, 0);
        f32x4 y0 = a00 + a01;    // cols 0..15   (c = lane&15)
        f32x4 y1 = a10 + a11;    // cols 16..31

        // C-layout -> row-layout via private-wave LDS transpose (proven).
        // write: row = quad*4+reg, col = 16h + r
        #pragma unroll
        for (int reg = 0; reg < 4; ++reg) {
            Tw[(quad * 4 + reg) * 33 + r]      = y0[reg];
            Tw[(quad * 4 + reg) * 33 + 16 + r] = y1[reg];
        }
        // read: row = r, cols quad*8 + j   (2-way bank aliasing only: free)
        float ss = 0.f;
        #pragma unroll
        for (int j = 0; j < 8; ++j) {
            mm[j] = Tw[r * 33 + quad * 8 + j];
            ss = fmaf(mm[j], mm[j], ss);
        }
        // PER-STEP normalization (round-7 bits; deferral redraws the chaotic
        // chain's absmax — do not trade this margin for ~20 inst/step)
        ss += __shfl_xor(ss, 16);
        ss += __shfl_xor(ss, 32);
        float kk = 1.0f / (sqrtf(ss) + EPS_NORM);
        #pragma unroll
        for (int j = 0; j < 8; ++j) mm[j] *= kk;

        xc = xn;
        #pragma unroll
        for (int q = 0; q < 8; ++q) cur[q] = nxt[q];
    }

    // ---- readout (xc now holds x for site 255) ----
    {
        float sN, cN; __sincosf(HALF_PI_F * xc, &sN, &cN);
        const float* kn = ws + WS_CN;        // [f][a][10]
        float acc[10];
        #pragma unroll
        for (int c = 0; c < 10; ++c) acc[c] = 0.f;
        #pragma unroll
        for (int j = 0; j < 8; ++j) {
            int a = quad * 8 + j;
            float Ma = mm[j];
            #pragma unroll
            for (int c = 0; c < 10; ++c) {
                float fin = cN * kn[a * 10 + c] + sN * kn[320 + a * 10 + c];
                acc[c] = fmaf(Ma, fin, acc[c]);
            }
        }
        #pragma unroll
        for (int c = 0; c < 10; ++c) {
            acc[c] += __shfl_xor(acc[c], 16);
            acc[c] += __shfl_xor(acc[c], 32);
        }
        const unsigned bf = *(const unsigned*)(ws + WS_FLAG);
        if (quad == 0) {
            if (bf) {
                __hip_bfloat16* o = (__hip_bfloat16*)out;
                #pragma unroll
                for (int c = 0; c < 10; ++c)
                    o[(size_t)(b0 + r) * 10 + c] = __float2bfloat16(acc[c]);
            } else {
                float* o = (float*)out;
                #pragma unroll
                for (int c = 0; c < 10; ++c)
                    o[(size_t)(b0 + r) * 10 + c] = acc[c];
            }
        }
    }
}

// ---------------- launch ----------------
extern "C" void kernel_launch(void* const* d_in, const int* in_sizes, int n_in,
                              void* d_out, int out_size, void* d_ws, size_t ws_size,
                              hipStream_t stream) {
    float* ws = (float*)d_ws;
    aux_all<<<2557, 256, 0, stream>>>(d_in[0], d_in[1], d_in[2], d_in[3], ws);
    // 512 blocks x 4 waves x 16 samples = 32768 samples; 2048 waves = 2 waves/SIMD
    mps_mfma<<<512, 256, 0, stream>>>(ws, d_out);
}